// Round 3
// baseline (510.276 us; speedup 1.0000x reference)
//
#include <hip/hip_runtime.h>
#include <stdint.h>

typedef unsigned short u16;
typedef unsigned int   u32;
typedef __attribute__((ext_vector_type(8))) short bf16x8;
typedef __attribute__((ext_vector_type(4))) float f32x4;

#define EPS 1e-3f
#define NB 32
#define HW 56
#define CI 256
#define CM 128
#define PIX (NB*HW*HW)   // 100352

__device__ __forceinline__ float asf(u32 i){ union{u32 u; float f;} t; t.u=i; return t.f; }
__device__ __forceinline__ u16 f2bf(float f){
  union{float f; u32 u;} t; t.f = f;
  u32 x = t.u;
  return (u16)((x + 0x7fffu + ((x>>16)&1u)) >> 16);   // RNE
}

// ---------------- prep: MFMA-fragment-swizzled bf16 weights + BN fold ----------------
__global__ __launch_bounds__(256) void kprep(
    const float* __restrict__ w1, const float* __restrict__ b1, const float* __restrict__ g1,
    const float* __restrict__ be1, const float* __restrict__ m1, const float* __restrict__ v1,
    const float* __restrict__ b2, const float* __restrict__ g2,
    const float* __restrict__ be2, const float* __restrict__ m2, const float* __restrict__ v2,
    const float* __restrict__ w3,
    u16* __restrict__ w1s, u16* __restrict__ w3s,
    float* __restrict__ A1, float* __restrict__ B1,
    float* __restrict__ A2, float* __restrict__ B2){
  int i = blockIdx.x*256 + threadIdx.x;
  if (i < 32768){
    { // w1s: t(8) x kt(8) x lane(64) x 8
      int j = i & 7, lane = (i >> 3) & 63, kt = (i >> 9) & 7, t = i >> 12;
      int col = lane & 15, quad = lane >> 4;
      int n = t*16 + col, k = kt*32 + quad*8 + j;
      w1s[i] = f2bf(w1[k*CM + n]);
    }
    { // w3s: t(16) x kc(4) x lane(64) x 8
      int j = i & 7, lane = (i >> 3) & 63, kc = (i >> 9) & 3, t = i >> 11;
      int col = lane & 15, quad = lane >> 4;
      int n = t*16 + col, k = kc*32 + quad*8 + j;
      w3s[i] = f2bf(w3[k*CI + n]);
    }
  }
  if (i < 128){
    float s1 = g1[i] * rsqrtf(v1[i] + EPS);
    A1[i] = s1;
    B1[i] = b1[i]*s1 + be1[i] - m1[i]*s1;
    float s2 = g2[i] * rsqrtf(v2[i] + EPS);
    A2[i] = s2;
    B2[i] = b2[i]*s2 + be2[i] - m2[i]*s2;
  }
}

// ---------------- conv1 1x1 256->128 + BN + ReLU (MFMA bf16) ----------------
// REVERT to round-0 version: 256 thr (4 waves), K-chunked LDS staging (34.8 KB ->
// 4 blocks/CU, cross-block phase overlap). Round-1/2 rewrites were each slower
// (monolithic stage serializes HBM-burst vs MFMA-burst at 2 blocks/CU).
#define K1_LS 72   // A-tile row stride (u16)
__global__ __launch_bounds__(256) void k1(const float* __restrict__ x,
    const u16* __restrict__ w1s, const float* __restrict__ A1v,
    const float* __restrict__ B1v, u16* __restrict__ h1){
  __shared__ __align__(16) char smem[128*136*2];   // 34816 B (A-tile 18432; epilogue 34816)
  u16* As = (u16*)smem;                            // [128][72]
  const int tid  = threadIdx.x;
  const int lane = tid & 63, wv = tid >> 6;
  const int col  = lane & 15, quad = lane >> 4;
  const long p0 = (long)blockIdx.x * 128;
  f32x4 acc[8][2];
  #pragma unroll
  for (int a = 0; a < 8; a++)
    #pragma unroll
    for (int b = 0; b < 2; b++){ acc[a][b][0]=0.f; acc[a][b][1]=0.f; acc[a][b][2]=0.f; acc[a][b][3]=0.f; }
  for (int kc = 0; kc < 4; kc++){
    #pragma unroll
    for (int r = 0; r < 8; r++){
      int idx = r*256 + tid;
      int m = idx >> 4, f4 = idx & 15;
      float4 v = *(const float4*)(x + (p0+m)*CI + kc*64 + f4*4);
      u32 lo = (u32)f2bf(v.x) | ((u32)f2bf(v.y) << 16);
      u32 hi = (u32)f2bf(v.z) | ((u32)f2bf(v.w) << 16);
      *(uint2*)(As + m*K1_LS + f4*4) = make_uint2(lo, hi);
    }
    __syncthreads();
    #pragma unroll
    for (int ks = 0; ks < 2; ks++){
      const int kt = kc*2 + ks;
      bf16x8 bfr[2], af[8];
      #pragma unroll
      for (int nt = 0; nt < 2; nt++)
        bfr[nt] = *(const bf16x8*)(w1s + (size_t)(((wv*2+nt)*8 + kt)*64 + lane)*8);
      #pragma unroll
      for (int mt = 0; mt < 8; mt++)
        af[mt] = *(const bf16x8*)(As + (mt*16 + col)*K1_LS + ks*32 + quad*8);
      #pragma unroll
      for (int mt = 0; mt < 8; mt++)
        #pragma unroll
        for (int nt = 0; nt < 2; nt++)
          acc[mt][nt] = __builtin_amdgcn_mfma_f32_16x16x32_bf16(af[mt], bfr[nt], acc[mt][nt], 0, 0, 0);
    }
    __syncthreads();
  }
  // epilogue: BN + ReLU -> bf16, repack via LDS, vector store
  u16* outw = (u16*)smem;   // [128][136]
  #pragma unroll
  for (int nt = 0; nt < 2; nt++){
    int n = wv*32 + nt*16 + col;
    float a1 = A1v[n], b1v = B1v[n];
    #pragma unroll
    for (int mt = 0; mt < 8; mt++)
      #pragma unroll
      for (int reg = 0; reg < 4; reg++){
        int m = mt*16 + quad*4 + reg;
        outw[m*136 + n] = f2bf(fmaxf(acc[mt][nt][reg]*a1 + b1v, 0.f));
      }
  }
  __syncthreads();
  #pragma unroll
  for (int r = 0; r < 8; r++){
    int idx = r*256 + tid;
    int m = idx >> 4, u4 = idx & 15;
    uint4 v = *(const uint4*)(outw + m*136 + u4*8);
    *(uint4*)(h1 + (p0+m)*CM + u4*8) = v;
  }
}

// ---------------- fused: grouped 3x3 + BN + ReLU + conv3 + bias + residual + ReLU ----------------
// v4: TWO output rows per block (896 blocks, M=112). Halo staging 4 rows per 2
// output rows (2x vs 3x re-read), MFMA M=112 exact (no zero rows, no pad memset),
// 3.5 barriers/row. h2t XOR-swizzled [112][128] -> conflict-free phase-C ds_read_b128.
// LDS: tile 59136 + wsh 18432 = 77568 B -> 2 blocks/CU.
#define LSH1 132   // h1 tile stride (u16)
__global__ __launch_bounds__(512, 2) void k23(const u16* __restrict__ h1,
    const float* __restrict__ w2, const float* __restrict__ A2v,
    const float* __restrict__ B2v, const u16* __restrict__ w3s,
    const float* __restrict__ b3, const float* __restrict__ x,
    float* __restrict__ out){
  __shared__ __align__(16) char smem[4*HW*LSH1*2 + 4608*4];   // 59136 + 18432 = 77568
  u16*  tile = (u16*)smem;                                 // [4][56][132] bf16 (phase A/B)
  char* h2t  = smem;                                       // [112][128] bf16 swizzled (overlay)
  float* pre = (float*)smem;                               // [112][132] f32 (overlay, epilogue)
  float* wsh = (float*)(smem + 4*HW*LSH1*2);               // [4608] f32 w2 (live whole kernel)

  const int tid = threadIdx.x;
  // XCD swizzle: grid 896 = 8 * 112; XCD k gets 112 consecutive row-pair blocks.
  const int bid = blockIdx.x;
  const int blk = (bid & 7)*112 + (bid >> 3);
  const int y0 = (blk % 28) * 2;            // first output row within image
  const long p0 = (long)blk * 112;          // first output pixel (2 contiguous rows)

  // ---- phase A: stage w2 + h1 rows y0-1..y0+2 ----
  for (int i = tid; i < 1152; i += 512)
    ((float4*)wsh)[i] = ((const float4*)w2)[i];
  #pragma unroll
  for (int r = 0; r < 4; r++){
    const int yy = y0 + r - 1;
    const bool valid = (yy >= 0 && yy < HW);
    const uint4* src = (const uint4*)(h1 + ((long)p0 + (r-1)*HW)*CM);
    for (int i = tid; i < 896; i += 512){
      uint4 v = make_uint4(0u,0u,0u,0u);
      if (valid) v = src[i];
      int px = i >> 4, ch = (i & 15)*8;
      u16* d = tile + (r*HW + px)*LSH1 + ch;
      *(uint2*)d     = make_uint2(v.x, v.y);
      *(uint2*)(d+4) = make_uint2(v.z, v.w);
    }
  }
  __syncthreads();   // sync1: tile+wsh staged

  // ---- phase B: grouped 3x3 conv for both rows, fp32 VALU, results in regs ----
  const int q = tid >> 6, pos = tid & 63;   // q: channel-eighth, pos: pixel col
  const bool act = pos < HW;
  u16 ov[2][16];
  if (act){
    int ixo[3]; u32 mk[3];
    #pragma unroll
    for (int kx = 0; kx < 3; kx++){
      int c = pos + kx - 1;
      ixo[kx] = (c < 0 ? 0 : (c > 55 ? 55 : c)) * LSH1;
      mk[kx] = (c >= 0 && c < HW) ? 0xffffffffu : 0u;
    }
    #pragma unroll
    for (int rr = 0; rr < 2; rr++){
      #pragma unroll
      for (int gi = 0; gi < 4; gi++){
        const int cb = q*16 + gi*4;
        float a0=0.f, a1=0.f, a2=0.f, a3=0.f;
        #pragma unroll
        for (int ky = 0; ky < 3; ky++){
          const u16* trow = tile + (rr+ky)*HW*LSH1 + cb;
          #pragma unroll
          for (int kx = 0; kx < 3; kx++){
            uint2 hv = *(const uint2*)(trow + ixo[kx]);
            u32 hx = hv.x & mk[kx], hy = hv.y & mk[kx];
            float i0 = asf(hx<<16), i1 = asf(hx&0xffff0000u);
            float i2 = asf(hy<<16), i3 = asf(hy&0xffff0000u);
            const float* wp = wsh + ((ky*3+kx)*4)*CM + cb;
            float4 w0  = *(const float4*)(wp);
            float4 w1v = *(const float4*)(wp+CM);
            float4 w2v = *(const float4*)(wp+2*CM);
            float4 w3v = *(const float4*)(wp+3*CM);
            a0 += i0*w0.x + i1*w1v.x + i2*w2v.x + i3*w3v.x;
            a1 += i0*w0.y + i1*w1v.y + i2*w2v.y + i3*w3v.y;
            a2 += i0*w0.z + i1*w1v.z + i2*w2v.z + i3*w3v.z;
            a3 += i0*w0.w + i1*w1v.w + i2*w2v.w + i3*w3v.w;
          }
        }
        float av[4] = {a0, a1, a2, a3};
        #pragma unroll
        for (int co = 0; co < 4; co++){
          int c = cb + co;
          ov[rr][gi*4+co] = f2bf(fmaxf(av[co]*A2v[c] + B2v[c], 0.f));
        }
      }
    }
  }
  __syncthreads();   // sync2: ALL tile reads complete (tile region now dead)

  // ---- write h2 into swizzled overlay [112][128] ----
  if (act){
    #pragma unroll
    for (int rr = 0; rr < 2; rr++){
      int m = rr*HW + pos;
      #pragma unroll
      for (int hh = 0; hh < 2; hh++){
        uint4 pk;
        pk.x = (u32)ov[rr][hh*8+0] | ((u32)ov[rr][hh*8+1]<<16);
        pk.y = (u32)ov[rr][hh*8+2] | ((u32)ov[rr][hh*8+3]<<16);
        pk.z = (u32)ov[rr][hh*8+4] | ((u32)ov[rr][hh*8+5]<<16);
        pk.w = (u32)ov[rr][hh*8+6] | ((u32)ov[rr][hh*8+7]<<16);
        int byte = m*256 + ((q*32 + hh*16) ^ ((m & 7) << 4));
        *(uint4*)(h2t + byte) = pk;
      }
    }
  }
  __syncthreads();   // sync3: h2t ready

  // ---- phase C: conv3 MFMA. M=112 (7 m-tiles), wave wv owns N=[wv*32, wv*32+32) ----
  const int lane = tid & 63, wv = tid >> 6;
  const int col  = lane & 15, quad = lane >> 4;
  f32x4 acc3[7][2];
  #pragma unroll
  for (int a = 0; a < 7; a++)
    #pragma unroll
    for (int b = 0; b < 2; b++){ acc3[a][b][0]=0.f; acc3[a][b][1]=0.f; acc3[a][b][2]=0.f; acc3[a][b][3]=0.f; }
  float bias[2];
  #pragma unroll
  for (int nt = 0; nt < 2; nt++) bias[nt] = b3[wv*32 + nt*16 + col];
  #pragma unroll
  for (int kc = 0; kc < 4; kc++){
    bf16x8 bfr[2];
    #pragma unroll
    for (int nt = 0; nt < 2; nt++)
      bfr[nt] = *(const bf16x8*)(w3s + (size_t)(((wv*2+nt)*4 + kc)*64 + lane)*8);  // coalesced, L2
    #pragma unroll
    for (int mt = 0; mt < 7; mt++){
      int row = mt*16 + col;
      bf16x8 af = *(const bf16x8*)(h2t + row*256 + ((kc*64 + quad*16) ^ ((row & 7) << 4)));
      #pragma unroll
      for (int nt = 0; nt < 2; nt++)
        acc3[mt][nt] = __builtin_amdgcn_mfma_f32_16x16x32_bf16(af, bfr[nt], acc3[mt][nt], 0, 0, 0);
    }
  }
  __syncthreads();   // sync4: h2t reads done (region free for pre overlay)

  // ---- epilogue: two n-halves through pre, +residual +ReLU ----
  #pragma unroll
  for (int h = 0; h < 2; h++){
    if ((wv >> 2) == h){
      #pragma unroll
      for (int mt = 0; mt < 7; mt++)
        #pragma unroll
        for (int nt = 0; nt < 2; nt++)
          #pragma unroll
          for (int reg = 0; reg < 4; reg++){
            int m = mt*16 + quad*4 + reg;
            pre[m*132 + (wv&3)*32 + nt*16 + col] = acc3[mt][nt][reg] + bias[nt];
          }
    }
    __syncthreads();   // pre half ready
    #pragma unroll
    for (int it = 0; it < 7; it++){
      int i = tid + it*512;          // 3584 = 7*512 exactly
      int m = i >> 5, f4 = i & 31;
      float4 xv = *(const float4*)(x + (p0+m)*CI + h*128 + f4*4);
      float4 pv = *(const float4*)(pre + m*132 + f4*4);
      float4 o;
      o.x = fmaxf(pv.x + xv.x, 0.f);
      o.y = fmaxf(pv.y + xv.y, 0.f);
      o.z = fmaxf(pv.z + xv.z, 0.f);
      o.w = fmaxf(pv.w + xv.w, 0.f);
      *(float4*)(out + (p0+m)*CI + h*128 + f4*4) = o;
    }
    __syncthreads();   // pre half consumed
  }
}

extern "C" void kernel_launch(void* const* d_in, const int* in_sizes, int n_in,
                              void* d_out, int out_size, void* d_ws, size_t ws_size,
                              hipStream_t stream){
  (void)in_sizes; (void)n_in; (void)out_size; (void)ws_size;
  const float* x   = (const float*)d_in[0];
  const float* w1  = (const float*)d_in[1];
  const float* b1  = (const float*)d_in[2];
  const float* g1  = (const float*)d_in[3];
  const float* be1 = (const float*)d_in[4];
  const float* m1  = (const float*)d_in[5];
  const float* v1  = (const float*)d_in[6];
  const float* w2  = (const float*)d_in[7];
  const float* b2  = (const float*)d_in[8];
  const float* g2  = (const float*)d_in[9];
  const float* be2 = (const float*)d_in[10];
  const float* m2  = (const float*)d_in[11];
  const float* v2  = (const float*)d_in[12];
  const float* w3  = (const float*)d_in[13];
  const float* b3  = (const float*)d_in[14];

  char* ws = (char*)d_ws;
  u16* h1  = (u16*)ws;                                  // 25.69 MB
  u16* w1s = (u16*)(ws + (size_t)PIX*CM*2);             // 64 KB
  u16* w3s = w1s + 32768;                               // 64 KB
  float* A1 = (float*)(w3s + 32768);
  float* B1 = A1 + 128;
  float* A2 = B1 + 128;
  float* B2 = A2 + 128;

  kprep<<<128, 256, 0, stream>>>(w1,b1,g1,be1,m1,v1,b2,g2,be2,m2,v2,w3,
                                 w1s,w3s,A1,B1,A2,B2);
  k1<<<PIX/128, 256, 0, stream>>>(x, w1s, A1, B1, h1);
  k23<<<NB*28, 512, 0, stream>>>(h1, w2, A2, B2, w3s, b3, x, (float*)d_out);
}

// Round 4
// 250.425 us; speedup vs baseline: 2.0376x; 2.0376x over previous
//
#include <hip/hip_runtime.h>
#include <stdint.h>

typedef unsigned short u16;
typedef unsigned int   u32;
typedef __attribute__((ext_vector_type(8))) short bf16x8;
typedef __attribute__((ext_vector_type(4))) float f32x4;

#define EPS 1e-3f
#define NB 32
#define HW 56
#define CI 256
#define CM 128
#define PIX (NB*HW*HW)   // 100352

__device__ __forceinline__ float asf(u32 i){ union{u32 u; float f;} t; t.u=i; return t.f; }
__device__ __forceinline__ u16 f2bf(float f){
  union{float f; u32 u;} t; t.f = f;
  u32 x = t.u;
  return (u16)((x + 0x7fffu + ((x>>16)&1u)) >> 16);   // RNE
}

// ---------------- prep: MFMA-fragment-swizzled bf16 weights + BN fold ----------------
// w1s: conv1 B-frags [8 t][8 kt][64 lane][8]
// w3s: conv3 B-frags [16 t][4 kc][64 lane][8]
// w2s: conv2 (grouped 3x3) block-diagonal B-frags [8 t][10 pv][64 lane][8]
//      pv 0..4 = hi bf16 of tap-pairs (0,1)(2,3)(4,5)(6,7)(8,pad); pv 5..9 = lo residual.
//      klocal = quad*8+j: <16 -> tapA ci 0..15, >=16 -> tapB ci 0..15.
//      nonzero iff (ci>>2) == (col>>2)  (group-diagonal within the 16-ch slice).
__global__ __launch_bounds__(256) void kprep(
    const float* __restrict__ w1, const float* __restrict__ b1, const float* __restrict__ g1,
    const float* __restrict__ be1, const float* __restrict__ m1, const float* __restrict__ v1,
    const float* __restrict__ w2, const float* __restrict__ b2, const float* __restrict__ g2,
    const float* __restrict__ be2, const float* __restrict__ m2, const float* __restrict__ v2,
    const float* __restrict__ w3,
    u16* __restrict__ w1s, u16* __restrict__ w3s, u16* __restrict__ w2s,
    float* __restrict__ A1, float* __restrict__ B1,
    float* __restrict__ A2, float* __restrict__ B2){
  int i = blockIdx.x*256 + threadIdx.x;
  if (i < 32768){
    { // w1s
      int j = i & 7, lane = (i >> 3) & 63, kt = (i >> 9) & 7, t = i >> 12;
      int col = lane & 15, quad = lane >> 4;
      int n = t*16 + col, k = kt*32 + quad*8 + j;
      w1s[i] = f2bf(w1[k*CM + n]);
    }
    { // w3s
      int j = i & 7, lane = (i >> 3) & 63, kc = (i >> 9) & 3, t = i >> 11;
      int col = lane & 15, quad = lane >> 4;
      int n = t*16 + col, k = kc*32 + quad*8 + j;
      w3s[i] = f2bf(w3[k*CI + n]);
    }
  }
  if (i < 40960){ // w2s
    int j = i & 7, lane = (i >> 3) & 63;
    int pv = (i >> 9) % 10, t = (i >> 9) / 10;
    int pp = pv % 5; bool lo = pv >= 5;
    int col = lane & 15, quad = lane >> 4;
    int klocal = quad*8 + j;
    int tap = (klocal < 16) ? 2*pp : 2*pp + 1;   // tap 9 (pp=4 hi-half) = invalid -> 0
    int c = klocal & 15;
    float wv = 0.f;
    if (tap <= 8 && (c >> 2) == (col >> 2))
      wv = w2[(tap*4 + (c & 3))*CM + t*16 + col];
    u16 hi = f2bf(wv);
    if (!lo) w2s[i] = hi;
    else     w2s[i] = f2bf(wv - asf((u32)hi << 16));
  }
  if (i < 128){
    float s1 = g1[i] * rsqrtf(v1[i] + EPS);
    A1[i] = s1;
    B1[i] = b1[i]*s1 + be1[i] - m1[i]*s1;
    float s2 = g2[i] * rsqrtf(v2[i] + EPS);
    A2[i] = s2;
    B2[i] = b2[i]*s2 + be2[i] - m2[i]*s2;
  }
}

// ---------------- conv1 1x1 256->128 + BN + ReLU (MFMA bf16) ----------------
// round-0 version (best measured): 256 thr, K-chunked LDS, 4 blocks/CU.
#define K1_LS 72   // A-tile row stride (u16)
__global__ __launch_bounds__(256) void k1(const float* __restrict__ x,
    const u16* __restrict__ w1s, const float* __restrict__ A1v,
    const float* __restrict__ B1v, u16* __restrict__ h1){
  __shared__ __align__(16) char smem[128*136*2];
  u16* As = (u16*)smem;                            // [128][72]
  const int tid  = threadIdx.x;
  const int lane = tid & 63, wv = tid >> 6;
  const int col  = lane & 15, quad = lane >> 4;
  const long p0 = (long)blockIdx.x * 128;
  f32x4 acc[8][2];
  #pragma unroll
  for (int a = 0; a < 8; a++)
    #pragma unroll
    for (int b = 0; b < 2; b++){ acc[a][b][0]=0.f; acc[a][b][1]=0.f; acc[a][b][2]=0.f; acc[a][b][3]=0.f; }
  for (int kc = 0; kc < 4; kc++){
    #pragma unroll
    for (int r = 0; r < 8; r++){
      int idx = r*256 + tid;
      int m = idx >> 4, f4 = idx & 15;
      float4 v = *(const float4*)(x + (p0+m)*CI + kc*64 + f4*4);
      u32 lo = (u32)f2bf(v.x) | ((u32)f2bf(v.y) << 16);
      u32 hi = (u32)f2bf(v.z) | ((u32)f2bf(v.w) << 16);
      *(uint2*)(As + m*K1_LS + f4*4) = make_uint2(lo, hi);
    }
    __syncthreads();
    #pragma unroll
    for (int ks = 0; ks < 2; ks++){
      const int kt = kc*2 + ks;
      bf16x8 bfr[2], af[8];
      #pragma unroll
      for (int nt = 0; nt < 2; nt++)
        bfr[nt] = *(const bf16x8*)(w1s + (size_t)(((wv*2+nt)*8 + kt)*64 + lane)*8);
      #pragma unroll
      for (int mt = 0; mt < 8; mt++)
        af[mt] = *(const bf16x8*)(As + (mt*16 + col)*K1_LS + ks*32 + quad*8);
      #pragma unroll
      for (int mt = 0; mt < 8; mt++)
        #pragma unroll
        for (int nt = 0; nt < 2; nt++)
          acc[mt][nt] = __builtin_amdgcn_mfma_f32_16x16x32_bf16(af[mt], bfr[nt], acc[mt][nt], 0, 0, 0);
    }
    __syncthreads();
  }
  u16* outw = (u16*)smem;   // [128][136]
  #pragma unroll
  for (int nt = 0; nt < 2; nt++){
    int n = wv*32 + nt*16 + col;
    float a1 = A1v[n], b1v = B1v[n];
    #pragma unroll
    for (int mt = 0; mt < 8; mt++)
      #pragma unroll
      for (int reg = 0; reg < 4; reg++){
        int m = mt*16 + quad*4 + reg;
        outw[m*136 + n] = f2bf(fmaxf(acc[mt][nt][reg]*a1 + b1v, 0.f));
      }
  }
  __syncthreads();
  #pragma unroll
  for (int r = 0; r < 8; r++){
    int idx = r*256 + tid;
    int m = idx >> 4, u4 = idx & 15;
    uint4 v = *(const uint4*)(outw + m*136 + u4*8);
    *(uint4*)(h1 + (p0+m)*CM + u4*8) = v;
  }
}

// ---------------- fused: grouped 3x3 (MFMA!) + BN + ReLU + conv3 + bias + residual + ReLU ----------------
// v5: R2 structure (1 row/block, 512 thr) but phase B moved to the matrix pipe:
// block-diagonal MFMA over 4-group N-tiles, taps selected per-quad in the A-frag
// address, border masking via v_and on fragments, weights hi+lo bf16 (~f32 quality).
// wsh gone (B-frags stream from L2). h2t XOR-swizzled -> conflict-free conv3 reads.
// LDS: tile 45696 + h2t 16384 = 62080 B -> 2 blocks/CU. 6 barriers.
#define LSH1 136   // h1 tile stride (u16), 272 B rows: 16B-aligned, bank stride 4
__global__ __launch_bounds__(512, 2) void k23(const u16* __restrict__ h1,
    const u16* __restrict__ w2s, const float* __restrict__ A2v,
    const float* __restrict__ B2v, const u16* __restrict__ w3s,
    const float* __restrict__ b3, const float* __restrict__ x,
    float* __restrict__ out){
  __shared__ __align__(16) char smem[3*HW*LSH1*2 + 64*256];   // 45696 + 16384 = 62080
  u16*  tile = (u16*)smem;                     // [3][56][136] bf16 (phase A/B)
  char* h2t  = smem + 3*HW*LSH1*2;             // [64] rows x 256 B, XOR-swizzled
  float* pre = (float*)smem;                   // [64][132] f32 (overlay, epilogue)

  const int tid = threadIdx.x;
  // XCD swizzle: grid 1792 = 8 * 224
  const int bid = blockIdx.x;
  const int blk = (bid & 7)*224 + (bid >> 3);
  const int y0 = blk % HW;
  const long p0 = (long)blk * HW;

  // ---- phase A: stage h1 rows y0-1..y0+1 ----
  #pragma unroll
  for (int r = 0; r < 3; r++){
    const int yy = y0 + r - 1;
    const bool valid = (yy >= 0 && yy < HW);
    const uint4* src = (const uint4*)(h1 + (long)(blk - y0 + yy)*HW*CM);
    for (int i = tid; i < 896; i += 512){
      uint4 v = make_uint4(0u,0u,0u,0u);
      if (valid) v = src[i];
      int px = i >> 4, ch = (i & 15)*8;
      *(uint4*)(tile + (r*HW + px)*LSH1 + ch) = v;   // 16B-aligned (LSH1=136)
    }
  }
  __syncthreads();   // sync1: tile staged

  // ---- residual prefetch, n-half 0 ----
  float4 xr[4];
  #pragma unroll
  for (int it = 0; it < 4; it++){
    int i = tid + it*512;
    if (i < 1792){
      int m = i >> 5, f4 = i & 31;
      xr[it] = *(const float4*)(x + (p0+m)*CI + f4*4);
    }
  }

  const int lane = tid & 63, wv = tid >> 6;
  const int col  = lane & 15, quad = lane >> 4;

  // ---- phase B: grouped 3x3 via block-diagonal MFMA ----
  // wave (mh, nq): m-tiles {2mh,2mh+1} (M=64, rows>=56 masked), n-tiles {2nq,2nq+1}.
  const int mh = wv >> 2, nq = wv & 3;
  f32x4 acc2[2][2];
  #pragma unroll
  for (int a = 0; a < 2; a++)
    #pragma unroll
    for (int b = 0; b < 2; b++){ acc2[a][b][0]=0.f; acc2[a][b][1]=0.f; acc2[a][b][2]=0.f; acc2[a][b][3]=0.f; }
  #pragma unroll
  for (int pp = 0; pp < 5; pp++){
    const int tA = 2*pp, tB = (pp < 4) ? 2*pp + 1 : 8;
    const int dyA = tA/3, dxA = tA%3, dyB = tB/3, dxB = tB%3;
    const int dy = (quad < 2) ? dyA : dyB;
    const int dx = (quad < 2) ? dxA : dxB;
    bf16x8 bh[2], bl[2];
    #pragma unroll
    for (int ntl = 0; ntl < 2; ntl++){
      int nt = nq*2 + ntl;
      bh[ntl] = *(const bf16x8*)(w2s + (size_t)((nt*10 + pp)*64 + lane)*8);
      bl[ntl] = *(const bf16x8*)(w2s + (size_t)((nt*10 + 5 + pp)*64 + lane)*8);
    }
    #pragma unroll
    for (int mtl = 0; mtl < 2; mtl++){
      int px = (mh*2 + mtl)*16 + col;
      int sx = px + dx - 1;
      u32 mk = (px < HW && sx >= 0 && sx < HW) ? 0xffffffffu : 0u;
      int sxc = sx < 0 ? 0 : (sx > 55 ? 55 : sx);
      const u16* abase = tile + (dy*HW + sxc)*LSH1 + (quad & 1)*8;
      #pragma unroll
      for (int ntl = 0; ntl < 2; ntl++){
        int nt = nq*2 + ntl;
        union { bf16x8 v; u32 w[4]; } af;
        af.v = *(const bf16x8*)(abase + nt*16);
        af.w[0] &= mk; af.w[1] &= mk; af.w[2] &= mk; af.w[3] &= mk;
        acc2[mtl][ntl] = __builtin_amdgcn_mfma_f32_16x16x32_bf16(af.v, bh[ntl], acc2[mtl][ntl], 0, 0, 0);
        acc2[mtl][ntl] = __builtin_amdgcn_mfma_f32_16x16x32_bf16(af.v, bl[ntl], acc2[mtl][ntl], 0, 0, 0);
      }
    }
  }
  // BN + ReLU -> bf16, write h2t swizzled (rows >= 56 forced to zero)
  #pragma unroll
  for (int ntl = 0; ntl < 2; ntl++){
    int co = (nq*2 + ntl)*16 + col;
    float a2 = A2v[co], b2v = B2v[co];
    #pragma unroll
    for (int mtl = 0; mtl < 2; mtl++)
      #pragma unroll
      for (int reg = 0; reg < 4; reg++){
        int m = (mh*2 + mtl)*16 + quad*4 + reg;
        float v = acc2[mtl][ntl][reg]*a2 + b2v;
        u16 hv = (m < HW) ? f2bf(fmaxf(v, 0.f)) : (u16)0;
        *(u16*)(h2t + m*256 + ((co*2) ^ ((m & 7) << 4))) = hv;
      }
  }
  __syncthreads();   // sync2: h2t ready (also: all tile reads done)

  // ---- phase C: conv3 MFMA. M=64, wave wv owns N=[wv*32, wv*32+32) ----
  f32x4 acc3[4][2];
  #pragma unroll
  for (int a = 0; a < 4; a++)
    #pragma unroll
    for (int b = 0; b < 2; b++){ acc3[a][b][0]=0.f; acc3[a][b][1]=0.f; acc3[a][b][2]=0.f; acc3[a][b][3]=0.f; }
  float bias[2];
  #pragma unroll
  for (int nt = 0; nt < 2; nt++) bias[nt] = b3[wv*32 + nt*16 + col];
  #pragma unroll
  for (int kc = 0; kc < 4; kc++){
    bf16x8 bfr[2];
    #pragma unroll
    for (int nt = 0; nt < 2; nt++)
      bfr[nt] = *(const bf16x8*)(w3s + (size_t)(((wv*2+nt)*4 + kc)*64 + lane)*8);
    #pragma unroll
    for (int mt = 0; mt < 4; mt++){
      int row = mt*16 + col;
      bf16x8 af = *(const bf16x8*)(h2t + row*256 + ((kc*64 + quad*16) ^ ((row & 7) << 4)));
      #pragma unroll
      for (int nt = 0; nt < 2; nt++)
        acc3[mt][nt] = __builtin_amdgcn_mfma_f32_16x16x32_bf16(af, bfr[nt], acc3[mt][nt], 0, 0, 0);
    }
  }

  // ---- epilogue: two n-halves through pre (overlays tile), +residual +ReLU ----
  if (wv < 4){
    #pragma unroll
    for (int mt = 0; mt < 4; mt++)
      #pragma unroll
      for (int nt = 0; nt < 2; nt++)
        #pragma unroll
        for (int reg = 0; reg < 4; reg++){
          int m = mt*16 + quad*4 + reg;
          pre[m*132 + (wv&3)*32 + nt*16 + col] = acc3[mt][nt][reg] + bias[nt];
        }
  }
  __syncthreads();   // sync3: pre half-0 ready
  #pragma unroll
  for (int it = 0; it < 4; it++){
    int i = tid + it*512;
    if (i < 1792){
      int m = i >> 5, f4 = i & 31;
      float4 pv = *(const float4*)(pre + m*132 + f4*4);
      float4 o;
      o.x = fmaxf(pv.x + xr[it].x, 0.f);
      o.y = fmaxf(pv.y + xr[it].y, 0.f);
      o.z = fmaxf(pv.z + xr[it].z, 0.f);
      o.w = fmaxf(pv.w + xr[it].w, 0.f);
      *(float4*)(out + (p0+m)*CI + f4*4) = o;
    }
  }
  __syncthreads();   // sync4: pre half-0 consumed

  if (wv >= 4){
    #pragma unroll
    for (int mt = 0; mt < 4; mt++)
      #pragma unroll
      for (int nt = 0; nt < 2; nt++)
        #pragma unroll
        for (int reg = 0; reg < 4; reg++){
          int m = mt*16 + quad*4 + reg;
          pre[m*132 + (wv&3)*32 + nt*16 + col] = acc3[mt][nt][reg] + bias[nt];
        }
  }
  __syncthreads();   // sync5: pre half-1 ready
  #pragma unroll
  for (int it = 0; it < 4; it++){
    int i = tid + it*512;
    if (i < 1792){
      int m = i >> 5, f4 = i & 31;
      float4 xv = *(const float4*)(x + (p0+m)*CI + 128 + f4*4);
      float4 pv = *(const float4*)(pre + m*132 + f4*4);
      float4 o;
      o.x = fmaxf(pv.x + xv.x, 0.f);
      o.y = fmaxf(pv.y + xv.y, 0.f);
      o.z = fmaxf(pv.z + xv.z, 0.f);
      o.w = fmaxf(pv.w + xv.w, 0.f);
      *(float4*)(out + (p0+m)*CI + 128 + f4*4) = o;
    }
  }
}

extern "C" void kernel_launch(void* const* d_in, const int* in_sizes, int n_in,
                              void* d_out, int out_size, void* d_ws, size_t ws_size,
                              hipStream_t stream){
  (void)in_sizes; (void)n_in; (void)out_size; (void)ws_size;
  const float* x   = (const float*)d_in[0];
  const float* w1  = (const float*)d_in[1];
  const float* b1  = (const float*)d_in[2];
  const float* g1  = (const float*)d_in[3];
  const float* be1 = (const float*)d_in[4];
  const float* m1  = (const float*)d_in[5];
  const float* v1  = (const float*)d_in[6];
  const float* w2  = (const float*)d_in[7];
  const float* b2  = (const float*)d_in[8];
  const float* g2  = (const float*)d_in[9];
  const float* be2 = (const float*)d_in[10];
  const float* m2  = (const float*)d_in[11];
  const float* v2  = (const float*)d_in[12];
  const float* w3  = (const float*)d_in[13];
  const float* b3  = (const float*)d_in[14];

  char* ws = (char*)d_ws;
  u16* h1  = (u16*)ws;                                  // 25.69 MB
  u16* w1s = (u16*)(ws + (size_t)PIX*CM*2);             // 64 KB
  u16* w3s = w1s + 32768;                               // 64 KB
  float* A1 = (float*)(w3s + 32768);
  float* B1 = A1 + 128;
  float* A2 = B1 + 128;
  float* B2 = A2 + 128;
  u16* w2s = (u16*)(B2 + 128);                          // 80 KB (16B-aligned offset)

  kprep<<<160, 256, 0, stream>>>(w1,b1,g1,be1,m1,v1,w2,b2,g2,be2,m2,v2,w3,
                                 w1s,w3s,w2s,A1,B1,A2,B2);
  k1<<<PIX/128, 256, 0, stream>>>(x, w1s, A1, B1, h1);
  k23<<<NB*HW, 512, 0, stream>>>(h1, w2s, A2, B2, w3s, b3, x, (float*)d_out);
}